// Round 3
// baseline (658.009 us; speedup 1.0000x reference)
//
#include <hip/hip_runtime.h>
#include <hip/hip_bf16.h>
#include <stdint.h>

#define M_NODES 100000
#define DIM     256
#define N_EDGES 3200000
#define CAP     80          // padded-CSR capacity; degrees ~Poisson(32), P(>=80) ~ 1e-11/row
#define CHUNK   2048        // edges per partition block (small: 1563 blocks -> 6/CU)
#define NCHUNK  1563        // ceil(N_EDGES / CHUNK)
#define NB      391         // row>>8 buckets (256 rows each), covers 100096 rows
#define BCAP    9216        // per-bucket slot capacity; mean 8184, std ~90 -> +11 sigma

typedef __bf16 bf16x8 __attribute__((ext_vector_type(8)));
typedef float  f32x4  __attribute__((ext_vector_type(4)));
typedef unsigned short u16x8 __attribute__((ext_vector_type(8)));

__device__ __forceinline__ unsigned short f2bf(float f) {
    unsigned u = __float_as_uint(f);
    u += 0x7FFF + ((u >> 16) & 1);          // round-to-nearest-even
    return (unsigned short)(u >> 16);
}
__device__ __forceinline__ float bf2f(unsigned short h) {
    return __uint_as_float(((unsigned)h) << 16);
}

// ---- W [k][n] fp32 -> Wt [n][k] bf16; also zero the NB bucket cursors ----
__global__ __launch_bounds__(256) void k_convert_wt(const float* __restrict__ W,
                                                    unsigned short* __restrict__ Wt,
                                                    int* __restrict__ cur) {
    int k = blockIdx.x, n = threadIdx.x;
    Wt[n * 256 + k] = f2bf(W[k * 256 + n]);
    int gid = k * 256 + n;
    if (gid < NB) cur[gid] = 0;
}

// ---- fused: even blocks = GEMM tile (S = X@W, bf16 MFMA);
//      odd blocks = partition chunk (bucket-major scatter of edges).
//      The two independent chains overlap on every CU: MFMA/L2-bound gemm
//      waves hide the scatter latency of part waves. ----
__global__ __launch_bounds__(256) void k_fused(const float* __restrict__ X,
                                               const unsigned short* __restrict__ Wt,
                                               unsigned short* __restrict__ Sb,
                                               const int* __restrict__ rows,
                                               const int* __restrict__ cols,
                                               const float* __restrict__ vals,
                                               uint64_t* __restrict__ part,
                                               int* __restrict__ cur) {
    __shared__ int cnt[NB];
    __shared__ int wcur[NB];
    int bid = blockIdx.x;
    int t   = threadIdx.x;

    if ((bid & 1) == 0) {
        // ---------------- GEMM path ----------------
        int wave = t >> 6;
        int lane = t & 63;
        int tile = (bid >> 1) * 4 + wave;      // 16-row m-tile
        if (tile >= M_NODES / 16) return;
        int m0   = tile * 16;
        int quad = lane >> 4;
        int r    = lane & 15;

        const float* aptr = X + (size_t)(m0 + r) * 256 + quad * 8;

        f32x4 acc[16];
#pragma unroll
        for (int tt = 0; tt < 16; ++tt) acc[tt] = {0.f, 0.f, 0.f, 0.f};

#pragma unroll
        for (int k0 = 0; k0 < 256; k0 += 32) {
            f32x4 a0 = *(const f32x4*)(aptr + k0);
            f32x4 a1 = *(const f32x4*)(aptr + k0 + 4);
            unsigned short au[8];
            au[0] = f2bf(a0.x); au[1] = f2bf(a0.y); au[2] = f2bf(a0.z); au[3] = f2bf(a0.w);
            au[4] = f2bf(a1.x); au[5] = f2bf(a1.y); au[6] = f2bf(a1.z); au[7] = f2bf(a1.w);
            bf16x8 a = *(bf16x8*)au;
#pragma unroll
            for (int tt = 0; tt < 16; ++tt) {
                bf16x8 b = *(const bf16x8*)(Wt + (size_t)(tt * 16 + r) * 256 + k0 + quad * 8);
                acc[tt] = __builtin_amdgcn_mfma_f32_16x16x32_bf16(a, b, acc[tt], 0, 0, 0);
            }
        }

#pragma unroll
        for (int tt = 0; tt < 16; ++tt)
#pragma unroll
            for (int i = 0; i < 4; ++i)
                Sb[(size_t)(m0 + quad * 4 + i) * 256 + tt * 16 + r] = f2bf(acc[tt][i]);
        return;
    }

    // ---------------- partition path ----------------
    int w    = bid >> 1;
    int base = w * CHUNK;
    int clen = N_EDGES - base; if (clen > CHUNK) clen = CHUNK;

    for (int i = t; i < NB; i += 256) cnt[i] = 0;
    __syncthreads();
    for (int i = t; i < clen; i += 256)
        atomicAdd(&cnt[rows[base + i] >> 8], 1);
    __syncthreads();

    for (int b = t; b < NB; b += 256)
        if (cnt[b]) wcur[b] = atomicAdd(&cur[b], cnt[b]);   // reserve range in bucket b
    __syncthreads();

    for (int i = t; i < clen; i += 256) {
        int   r = rows[base + i];
        int   c = cols[base + i];
        float v = vals[base + i];
        int   b = r >> 8;
        int pos = atomicAdd(&wcur[b], 1);
        if (pos < BCAP) {
            uint32_t lo = (uint32_t)c | ((uint32_t)(r & 255) << 17);
            part[(size_t)b * BCAP + pos] = ((uint64_t)__float_as_uint(v) << 32) | lo;
        }
    }
}

// ---- build padded CSR: one WG per bucket streams its CONTIGUOUS region;
//      LDS lcnt allocates row slots; counts written coalesced at the end.
//      1024 threads: 24 waves/CU at 391 blocks to hide stream latency. ----
__global__ __launch_bounds__(1024) void k_build3(const uint64_t* __restrict__ part,
                                                 const int* __restrict__ cur,
                                                 uint32_t* __restrict__ csr4,
                                                 int* __restrict__ counts) {
    __shared__ int lcnt[256];
    int b = blockIdx.x, t = threadIdx.x;
    if (t < 256) lcnt[t] = 0;
    int n = cur[b];
    if (n > BCAP) n = BCAP;
    __syncthreads();

    const uint64_t* p = part + (size_t)b * BCAP;
    for (int i = t; i < n; i += 1024) {
        uint64_t ent = p[i];
        uint32_t lo  = (uint32_t)ent;
        int   rl = (lo >> 17) & 255;
        int   c  = lo & 0x1FFFF;
        float v  = __uint_as_float((uint32_t)(ent >> 32));
        int qv = (int)(v * 32768.f + 0.5f);
        if (qv > 32767) qv = 32767;
        int pos = atomicAdd(&lcnt[rl], 1);
        if (pos < CAP)
            csr4[(size_t)(b * 256 + rl) * CAP + pos] = ((uint32_t)c << 15) | (uint32_t)qv;
    }
    __syncthreads();
    if (t < 256) counts[b * 256 + t] = lcnt[t];
}

// ---- spmm: one wave per row; 32 lanes x 8ch; 4 edges in flight per half ----
__global__ __launch_bounds__(256) void k_spmm(const int* __restrict__ counts,
                                              const uint32_t* __restrict__ csr4,
                                              const unsigned short* __restrict__ Sb,
                                              const float* __restrict__ bias,
                                              float* __restrict__ out) {
    int wave = threadIdx.x >> 6;
    int lane = threadIdx.x & 63;
    int r = blockIdx.x * 4 + wave;
    if (r >= M_NODES) return;
    int n = counts[r];
    if (n > CAP) n = CAP;
    const uint32_t* ep = csr4 + (size_t)r * CAP;
    int half = lane >> 5;
    int l    = lane & 31;

    float acc[8] = {0.f, 0.f, 0.f, 0.f, 0.f, 0.f, 0.f, 0.f};
    int j = 0;
    for (; j + 7 < n; j += 8) {
        uint32_t m0 = ep[j +     half];
        uint32_t m1 = ep[j + 2 + half];
        uint32_t m2 = ep[j + 4 + half];
        uint32_t m3 = ep[j + 6 + half];
        int c0 = m0 >> 15;  float v0 = (float)(m0 & 0x7FFF) * (1.f / 32768.f);
        int c1 = m1 >> 15;  float v1 = (float)(m1 & 0x7FFF) * (1.f / 32768.f);
        int c2 = m2 >> 15;  float v2 = (float)(m2 & 0x7FFF) * (1.f / 32768.f);
        int c3 = m3 >> 15;  float v3 = (float)(m3 & 0x7FFF) * (1.f / 32768.f);
        u16x8 s0 = *(const u16x8*)(Sb + (size_t)c0 * 256 + l * 8);
        u16x8 s1 = *(const u16x8*)(Sb + (size_t)c1 * 256 + l * 8);
        u16x8 s2 = *(const u16x8*)(Sb + (size_t)c2 * 256 + l * 8);
        u16x8 s3 = *(const u16x8*)(Sb + (size_t)c3 * 256 + l * 8);
#pragma unroll
        for (int i = 0; i < 8; ++i) acc[i] += bf2f(s0[i]) * v0;
#pragma unroll
        for (int i = 0; i < 8; ++i) acc[i] += bf2f(s1[i]) * v1;
#pragma unroll
        for (int i = 0; i < 8; ++i) acc[i] += bf2f(s2[i]) * v2;
#pragma unroll
        for (int i = 0; i < 8; ++i) acc[i] += bf2f(s3[i]) * v3;
    }
    for (; j + 1 < n; j += 2) {
        uint32_t m0 = ep[j + half];
        int c0 = m0 >> 15;  float v0 = (float)(m0 & 0x7FFF) * (1.f / 32768.f);
        u16x8 s0 = *(const u16x8*)(Sb + (size_t)c0 * 256 + l * 8);
#pragma unroll
        for (int i = 0; i < 8; ++i) acc[i] += bf2f(s0[i]) * v0;
    }
    if (j < n && half == 0) {
        uint32_t m0 = ep[j];
        int c0 = m0 >> 15;  float v0 = (float)(m0 & 0x7FFF) * (1.f / 32768.f);
        u16x8 s0 = *(const u16x8*)(Sb + (size_t)c0 * 256 + l * 8);
#pragma unroll
        for (int i = 0; i < 8; ++i) acc[i] += bf2f(s0[i]) * v0;
    }

#pragma unroll
    for (int i = 0; i < 8; ++i) acc[i] += __shfl(acc[i], lane + 32);

    if (half == 0) {
        f32x4 b0 = *(const f32x4*)(bias + l * 8);
        f32x4 b1 = *(const f32x4*)(bias + l * 8 + 4);
        f32x4 o0 = {acc[0] + b0.x, acc[1] + b0.y, acc[2] + b0.z, acc[3] + b0.w};
        f32x4 o1 = {acc[4] + b1.x, acc[5] + b1.y, acc[6] + b1.z, acc[7] + b1.w};
        float* op = out + (size_t)r * 256 + l * 8;
        *(f32x4*)op       = o0;
        *(f32x4*)(op + 4) = o1;
    }
}

extern "C" void kernel_launch(void* const* d_in, const int* in_sizes, int n_in,
                              void* d_out, int out_size, void* d_ws, size_t ws_size,
                              hipStream_t stream) {
    const float* X    = (const float*)d_in[0];
    const float* W    = (const float*)d_in[1];
    const float* bias = (const float*)d_in[2];
    const int*   er   = (const int*)d_in[3];
    const int*   ec   = (const int*)d_in[4];
    const float* ev   = (const float*)d_in[5];
    float* out = (float*)d_out;

    char* ws = (char*)d_ws;
    // layout (bytes):
    //   Wt     @ 0          131,072
    //   csr4   @ 131,072    32,030,720   (100096 rows * 80 * 4)
    //   cur    @ 32,161,792      1,564   (NB bucket cursors)
    //   counts @ 32,166,912    400,384   (100096 * 4)
    //   part   @ 32,567,296 28,827,648   (NB * BCAP * 8)
    //   Sb     @ 61,394,944 51,200,000   (NOT aliased: gemm runs concurrent with part)
    unsigned short* Wt     = (unsigned short*)ws;
    uint32_t*       csr4   = (uint32_t*)(ws + 131072);
    int*            cur    = (int*)(ws + 32161792);
    int*            counts = (int*)(ws + 32166912);
    uint64_t*       part   = (uint64_t*)(ws + 32567296);
    unsigned short* Sb     = (unsigned short*)(ws + 61394944);

    k_convert_wt<<<256,        256,  0, stream>>>(W, Wt, cur);
    k_fused     <<<2 * NCHUNK, 256,  0, stream>>>(X, Wt, Sb, er, ec, ev, part, cur);
    k_build3    <<<NB,         1024, 0, stream>>>(part, cur, csr4, counts);
    k_spmm      <<<25000,      256,  0, stream>>>(counts, csr4, Sb, bias, out);
}

// Round 4
// 621.539 us; speedup vs baseline: 1.0587x; 1.0587x over previous
//
#include <hip/hip_runtime.h>
#include <hip/hip_bf16.h>
#include <stdint.h>

#define M_NODES 100000
#define DIM     256
#define N_EDGES 3200000
#define CAP     80          // padded-CSR capacity; degrees ~Poisson(32), P(>=80) ~ 1e-11/row
#define NGB     782         // gemm blocks: ceil(100000 / 128)
#define NBB     1563        // build blocks: ceil(N_EDGES / 2048)

typedef __bf16 bf16x8 __attribute__((ext_vector_type(8)));
typedef float  f32x4  __attribute__((ext_vector_type(4)));
typedef unsigned short u16x8 __attribute__((ext_vector_type(8)));

__device__ __forceinline__ unsigned short f2bf(float f) {
    unsigned u = __float_as_uint(f);
    u += 0x7FFF + ((u >> 16) & 1);          // round-to-nearest-even
    return (unsigned short)(u >> 16);
}
__device__ __forceinline__ float bf2f(unsigned short h) {
    return __uint_as_float(((unsigned)h) << 16);
}

// ---- W [k][n] fp32 -> Wt [n][k] bf16; zero the per-row counts ----
__global__ __launch_bounds__(256) void k_convert_wt(const float* __restrict__ W,
                                                    unsigned short* __restrict__ Wt,
                                                    int* __restrict__ counts) {
    int k = blockIdx.x, n = threadIdx.x;
    Wt[n * 256 + k] = f2bf(W[k * 256 + n]);
    int gid = k * 256 + n;
    for (int i = gid; i < M_NODES + 96; i += 256 * 256) counts[i] = 0;
}

// ---- direct CSR build: one pass over raw edges; per-row slot via global
//      atomicAdd on counts[r] (3.2M atomics over 100K addresses -> ~512 per
//      cache line, no hotspot). Deletes the part/build pipeline entirely. ----
__global__ __launch_bounds__(256) void k_build(const int* __restrict__ rows,
                                               const int* __restrict__ cols,
                                               const float* __restrict__ vals,
                                               uint32_t* __restrict__ csr4,
                                               int* __restrict__ counts) {
    int base = blockIdx.x * 2048;
#pragma unroll
    for (int u = 0; u < 8; ++u) {
        int i = base + u * 256 + threadIdx.x;
        if (i < N_EDGES) {
            int   r = rows[i];
            int   c = cols[i];
            float v = vals[i];
            int q = (int)(v * 32768.f + 0.5f);
            if (q > 32767) q = 32767;
            int pos = atomicAdd(&counts[r], 1);
            if (pos < CAP)
                csr4[(size_t)r * CAP + pos] = ((uint32_t)c << 15) | (uint32_t)q;
        }
    }
}

// ---- S = X @ W: Wt staged in 64KB LDS (K-split, 2 phases), XOR-swizzled.
//      4 waves x 32 rows = 128 rows/block. Wt L2 traffic 3.2GB -> 100MB. ----
__global__ __launch_bounds__(256) void k_gemm(const float* __restrict__ X,
                                              const unsigned short* __restrict__ Wt,
                                              unsigned short* __restrict__ Sb) {
    __shared__ unsigned short wlds[32768];      // 64KB: 256 n-rows x 128 k bf16
    int t    = threadIdx.x;
    int wave = t >> 6;
    int lane = t & 63;
    int quad = lane >> 4;
    int r    = lane & 15;
    int m0   = blockIdx.x * 128 + wave * 32;    // this wave's 32 output rows

    int rowA = m0 + r;       if (rowA >= M_NODES) rowA = M_NODES - 1;
    int rowB = m0 + 16 + r;  if (rowB >= M_NODES) rowB = M_NODES - 1;
    const float* apA = X + (size_t)rowA * 256;
    const float* apB = X + (size_t)rowB * 256;

    f32x4 acc[32];
#pragma unroll
    for (int i = 0; i < 32; ++i) acc[i] = {0.f, 0.f, 0.f, 0.f};

    for (int kh = 0; kh < 2; ++kh) {
        if (kh) __syncthreads();                // all reads of phase-0 LDS done
        // stage Wt[0..255][kh*128 .. +128): 4096 16B chunks, 16 per thread
#pragma unroll
        for (int it = 0; it < 16; ++it) {
            int f   = it * 256 + t;
            int row = f >> 4;                   // 16 chunks of 16B per 256B row
            int ci  = f & 15;
            u16x8 v = *(const u16x8*)(Wt + row * 256 + kh * 128 + ci * 8);
            int lb  = (row * 256 + ci * 16) ^ ((row & 7) << 4);
            *(u16x8*)((char*)wlds + lb) = v;
        }
        __syncthreads();

#pragma unroll
        for (int ks = 0; ks < 4; ++ks) {
            int k0 = kh * 128 + ks * 32;
            f32x4 a0 = *(const f32x4*)(apA + k0 + quad * 8);
            f32x4 a1 = *(const f32x4*)(apA + k0 + quad * 8 + 4);
            f32x4 b0 = *(const f32x4*)(apB + k0 + quad * 8);
            f32x4 b1 = *(const f32x4*)(apB + k0 + quad * 8 + 4);
            unsigned short au[8], bu[8];
            au[0]=f2bf(a0.x); au[1]=f2bf(a0.y); au[2]=f2bf(a0.z); au[3]=f2bf(a0.w);
            au[4]=f2bf(a1.x); au[5]=f2bf(a1.y); au[6]=f2bf(a1.z); au[7]=f2bf(a1.w);
            bu[0]=f2bf(b0.x); bu[1]=f2bf(b0.y); bu[2]=f2bf(b0.z); bu[3]=f2bf(b0.w);
            bu[4]=f2bf(b1.x); bu[5]=f2bf(b1.y); bu[6]=f2bf(b1.z); bu[7]=f2bf(b1.w);
            bf16x8 aA = *(bf16x8*)au;
            bf16x8 aB = *(bf16x8*)bu;
            int lcol = ks * 64 + quad * 16;     // byte offset within 256B lds row
#pragma unroll
            for (int tt = 0; tt < 16; ++tt) {
                int row = tt * 16 + r;
                int lb  = (row * 256 + lcol) ^ ((row & 7) << 4);
                bf16x8 b = *(const bf16x8*)((char*)wlds + lb);
                acc[tt]      = __builtin_amdgcn_mfma_f32_16x16x32_bf16(aA, b, acc[tt],      0, 0, 0);
                acc[16 + tt] = __builtin_amdgcn_mfma_f32_16x16x32_bf16(aB, b, acc[16 + tt], 0, 0, 0);
            }
        }
    }

#pragma unroll
    for (int tt = 0; tt < 16; ++tt)
#pragma unroll
        for (int i = 0; i < 4; ++i) {
            int ra = m0 + quad * 4 + i;
            if (ra < M_NODES)
                Sb[(size_t)ra * 256 + tt * 16 + r] = f2bf(acc[tt][i]);
            int rb = m0 + 16 + quad * 4 + i;
            if (rb < M_NODES)
                Sb[(size_t)rb * 256 + tt * 16 + r] = f2bf(acc[16 + tt][i]);
        }
}

// ---- spmm: one wave per row; 32 lanes x 8ch; 4 edges in flight per half ----
__global__ __launch_bounds__(256) void k_spmm(const int* __restrict__ counts,
                                              const uint32_t* __restrict__ csr4,
                                              const unsigned short* __restrict__ Sb,
                                              const float* __restrict__ bias,
                                              float* __restrict__ out) {
    int wave = threadIdx.x >> 6;
    int lane = threadIdx.x & 63;
    int r = blockIdx.x * 4 + wave;
    if (r >= M_NODES) return;
    int n = counts[r];
    if (n > CAP) n = CAP;
    const uint32_t* ep = csr4 + (size_t)r * CAP;
    int half = lane >> 5;
    int l    = lane & 31;

    float acc[8] = {0.f, 0.f, 0.f, 0.f, 0.f, 0.f, 0.f, 0.f};
    int j = 0;
    for (; j + 7 < n; j += 8) {
        uint32_t m0 = ep[j +     half];
        uint32_t m1 = ep[j + 2 + half];
        uint32_t m2 = ep[j + 4 + half];
        uint32_t m3 = ep[j + 6 + half];
        int c0 = m0 >> 15;  float v0 = (float)(m0 & 0x7FFF) * (1.f / 32768.f);
        int c1 = m1 >> 15;  float v1 = (float)(m1 & 0x7FFF) * (1.f / 32768.f);
        int c2 = m2 >> 15;  float v2 = (float)(m2 & 0x7FFF) * (1.f / 32768.f);
        int c3 = m3 >> 15;  float v3 = (float)(m3 & 0x7FFF) * (1.f / 32768.f);
        u16x8 s0 = *(const u16x8*)(Sb + (size_t)c0 * 256 + l * 8);
        u16x8 s1 = *(const u16x8*)(Sb + (size_t)c1 * 256 + l * 8);
        u16x8 s2 = *(const u16x8*)(Sb + (size_t)c2 * 256 + l * 8);
        u16x8 s3 = *(const u16x8*)(Sb + (size_t)c3 * 256 + l * 8);
#pragma unroll
        for (int i = 0; i < 8; ++i) acc[i] += bf2f(s0[i]) * v0;
#pragma unroll
        for (int i = 0; i < 8; ++i) acc[i] += bf2f(s1[i]) * v1;
#pragma unroll
        for (int i = 0; i < 8; ++i) acc[i] += bf2f(s2[i]) * v2;
#pragma unroll
        for (int i = 0; i < 8; ++i) acc[i] += bf2f(s3[i]) * v3;
    }
    for (; j + 1 < n; j += 2) {
        uint32_t m0 = ep[j + half];
        int c0 = m0 >> 15;  float v0 = (float)(m0 & 0x7FFF) * (1.f / 32768.f);
        u16x8 s0 = *(const u16x8*)(Sb + (size_t)c0 * 256 + l * 8);
#pragma unroll
        for (int i = 0; i < 8; ++i) acc[i] += bf2f(s0[i]) * v0;
    }
    if (j < n && half == 0) {
        uint32_t m0 = ep[j];
        int c0 = m0 >> 15;  float v0 = (float)(m0 & 0x7FFF) * (1.f / 32768.f);
        u16x8 s0 = *(const u16x8*)(Sb + (size_t)c0 * 256 + l * 8);
#pragma unroll
        for (int i = 0; i < 8; ++i) acc[i] += bf2f(s0[i]) * v0;
    }

#pragma unroll
    for (int i = 0; i < 8; ++i) acc[i] += __shfl(acc[i], lane + 32);

    if (half == 0) {
        f32x4 b0 = *(const f32x4*)(bias + l * 8);
        f32x4 b1 = *(const f32x4*)(bias + l * 8 + 4);
        f32x4 o0 = {acc[0] + b0.x, acc[1] + b0.y, acc[2] + b0.z, acc[3] + b0.w};
        f32x4 o1 = {acc[4] + b1.x, acc[5] + b1.y, acc[6] + b1.z, acc[7] + b1.w};
        float* op = out + (size_t)r * 256 + l * 8;
        *(f32x4*)op       = o0;
        *(f32x4*)(op + 4) = o1;
    }
}

extern "C" void kernel_launch(void* const* d_in, const int* in_sizes, int n_in,
                              void* d_out, int out_size, void* d_ws, size_t ws_size,
                              hipStream_t stream) {
    const float* X    = (const float*)d_in[0];
    const float* W    = (const float*)d_in[1];
    const float* bias = (const float*)d_in[2];
    const int*   er   = (const int*)d_in[3];
    const int*   ec   = (const int*)d_in[4];
    const float* ev   = (const float*)d_in[5];
    float* out = (float*)d_out;

    char* ws = (char*)d_ws;
    // layout (bytes):
    //   Wt     @ 0          131,072
    //   csr4   @ 131,072    32,030,720   (100096 rows * 80 * 4)
    //   counts @ 32,161,792    400,384   (100096 * 4)
    //   Sb     @ 32,562,176 51,200,000   (ends 83,762,176)
    unsigned short* Wt     = (unsigned short*)ws;
    uint32_t*       csr4   = (uint32_t*)(ws + 131072);
    int*            counts = (int*)(ws + 32161792);
    unsigned short* Sb     = (unsigned short*)(ws + 32562176);

    k_convert_wt<<<256,   256, 0, stream>>>(W, Wt, counts);
    k_build     <<<NBB,   256, 0, stream>>>(er, ec, ev, csr4, counts);
    k_gemm      <<<NGB,   256, 0, stream>>>(X, Wt, Sb);
    k_spmm      <<<25000, 256, 0, stream>>>(counts, csr4, Sb, bias, out);
}